// Round 5
// baseline (148.348 us; speedup 1.0000x reference)
//
#include <hip/hip_runtime.h>

// LinearSiso IIR, round 5: R4 pipelined structure with compile fix —
// nontemporal stores go through a native clang ext_vector_type(4) alias
// (HIP_vector_type<float,4> is rejected by __builtin_nontemporal_store).

constexpr int T_LEN = 16384;
constexpr int HALF  = 8192;   // samples per half
constexpr int NCH   = 256;    // threads = chunks per half
constexpr int LCH   = 32;     // samples per chunk
constexpr int NQ    = 8;      // float4 quarters per chunk
constexpr int NSTG  = 8;      // stage iterations: HALF/4/NCH

typedef float vfloat4 __attribute__((ext_vector_type(4)));   // native vec for nt-store

// physical float4 slot for logical (chunk t, quarter q)
__device__ __forceinline__ int swz(int t, int q) {
    return t * NQ + (q ^ (t & (NQ - 1)));
}

__device__ __forceinline__ void nt_store4(float4* dst, float4 v) {
    vfloat4 nv; nv.x = v.x; nv.y = v.y; nv.z = v.z; nv.w = v.w;
    __builtin_nontemporal_store(nv, (vfloat4*)dst);
}

__global__ __launch_bounds__(NCH, 4) void iir_kernel(
    const float* __restrict__ bco, const float* __restrict__ aco,
    const float* __restrict__ u,   const float* __restrict__ y_init,
    const float* __restrict__ u_init, float* __restrict__ y)
{
    __shared__ float4 lds[HALF / 4];       // 32 KB half-row buffer (swizzled)
    __shared__ float sh_wt1[4], sh_wt2[4]; // per-wave scan totals
    __shared__ float sh_carry[3];          // y[8191], y[8190], u[8191] of half0

    const int row  = blockIdx.x;
    const int tid  = threadIdx.x;
    const int lane = tid & 63;
    const int wave = tid >> 6;

    const float4* __restrict__ u4 = (const float4*)(u + (size_t)row * T_LEN);
    float4*       __restrict__ y4 = (float4*)(y + (size_t)row * T_LEN);
    const float*  ldsf = (const float*)lds;

    // ---- issue half-0 stage-in loads immediately (hide behind preamble) ----
    float4 r[NSTG];
    #pragma unroll
    for (int s = 0; s < NSTG; ++s) r[s] = u4[s * NCH + tid];

    const float b0 = bco[0], b1 = bco[1];
    const float a1 = aco[0], a2 = aco[1];

    // ---- chunk-transition matrix M (LCH steps) and powers M^(2^k), k=0..6 ----
    float pa = 1.f, pb = 0.f;
    #pragma unroll
    for (int k = 0; k <= LCH - 2; ++k) { float pn = fmaf(-a2, pb, -(a1 * pa)); pb = pa; pa = pn; }
    const float pL2 = pa, pL3 = pb;
    const float pL1 = fmaf(-a2, pL3, -(a1 * pL2));
    float m11[7], m12[7], m21[7], m22[7];
    m11[0] = pL1; m12[0] = -a2 * pL2; m21[0] = pL2; m22[0] = -a2 * pL3;
    #pragma unroll
    for (int k = 1; k < 7; ++k) {   // square
        m11[k] = fmaf(m11[k-1], m11[k-1], m12[k-1] * m21[k-1]);
        m12[k] = fmaf(m11[k-1], m12[k-1], m12[k-1] * m22[k-1]);
        m21[k] = fmaf(m21[k-1], m11[k-1], m22[k-1] * m21[k-1]);
        m22[k] = fmaf(m21[k-1], m12[k-1], m22[k-1] * m22[k-1]);
    }
    // per-lane P = M^(lane+1) via binary decomposition (powers commute)
    float P11 = 1.f, P12 = 0.f, P21 = 0.f, P22 = 1.f;
    {
        const int e = lane + 1;
        #pragma unroll
        for (int k = 0; k < 7; ++k) {
            if ((e >> k) & 1) {
                float n11 = fmaf(m11[k], P11, m12[k] * P21);
                float n12 = fmaf(m11[k], P12, m12[k] * P22);
                float n21 = fmaf(m21[k], P11, m22[k] * P21);
                float n22 = fmaf(m21[k], P12, m22[k] * P22);
                P11 = n11; P12 = n12; P21 = n21; P22 = n22;
            }
        }
    }

    // ---- commit half-0 stage-in to LDS ----
    #pragma unroll
    for (int s = 0; s < NSTG; ++s) {
        const int g = s * NCH + tid;
        lds[swz(g >> 3, g & 7)] = r[s];
    }

#define IIR_STEP(UC, OUTV)                                        \
    {                                                             \
        float x_ = fmaf(b0, (UC), b1 * up);                       \
        (OUTV) = fmaf(-a2, y2, fmaf(-a1, y1, x_));                \
        y2 = y1; y1 = (OUTV); up = (UC);                          \
    }

    #pragma unroll 1
    for (int h = 0; h < 2; ++h) {
        __syncthreads();   // staged u visible

        // u[chunk_base - 1]
        float up0;
        if (tid == 0) up0 = (h == 0) ? u_init[2 * row] : sh_carry[2];
        else          up0 = ldsf[swz(tid - 1, 7) * 4 + 3];

        // ---- Phase A: zero-state response of own chunk ----
        float up = up0, y1 = 0.f, y2 = 0.f;
        #pragma unroll
        for (int q = 0; q < NQ; ++q) {
            float4 v = lds[swz(tid, q)];
            float t0, t1, t2, t3;
            IIR_STEP(v.x, t0); IIR_STEP(v.y, t1);
            IIR_STEP(v.z, t2); IIR_STEP(v.w, t3);
            (void)t0; (void)t1; (void)t2; (void)t3;
        }
        float v1 = y1, v2 = y2;                 // e_c
        if (tid == NCH - 1 && h == 0) sh_carry[2] = up;   // u[8191]

        // ---- prefetch half-1 u into registers; loads fly during scan + C ----
        if (h == 0) {
            #pragma unroll
            for (int s = 0; s < NSTG; ++s)
                r[s] = u4[(HALF / 4) + s * NCH + tid];
        }

        // fold initial state into e_0:  e'_0 = e_0 + M s0
        float s01 = 0.f, s02 = 0.f;
        if (tid == 0) {
            s01 = (h == 0) ? y_init[2 * row]     : sh_carry[0];
            s02 = (h == 0) ? y_init[2 * row + 1] : sh_carry[1];
            v1 = fmaf(m11[0], s01, fmaf(m12[0], s02, v1));
            v2 = fmaf(m21[0], s01, fmaf(m22[0], s02, v2));
        }

        // ---- intra-wave inclusive scan: v_c += M^d v_{c-d}, d=1..32 ----
        #pragma unroll
        for (int k = 0; k < 6; ++k) {
            const int d = 1 << k;
            float t1 = __shfl_up(v1, d);
            float t2 = __shfl_up(v2, d);
            if (lane >= d) {
                v1 = fmaf(m11[k], t1, fmaf(m12[k], t2, v1));
                v2 = fmaf(m21[k], t1, fmaf(m22[k], t2, v2));
            }
        }
        if (lane == 63) { sh_wt1[wave] = v1; sh_wt2[wave] = v2; }
        __syncthreads();

        // ---- cross-wave: Q_w = sum_{v<w} M^64(w-1-v) W_v ----
        float q1 = 0.f, q2 = 0.f;
        for (int w = 0; w < wave; ++w) {
            float n1 = fmaf(m11[6], q1, fmaf(m12[6], q2, sh_wt1[w]));
            float n2 = fmaf(m21[6], q1, fmaf(m22[6], q2, sh_wt2[w]));
            q1 = n1; q2 = n2;
        }
        // global inclusive prefix for this thread
        float w1 = fmaf(P11, q1, fmaf(P12, q2, v1));
        float w2 = fmaf(P21, q1, fmaf(P22, q2, v2));
        // exclusive: start state s_c = w'_{c-1}
        float x1 = __shfl_up(w1, 1);
        float x2 = __shfl_up(w2, 1);
        if (lane == 0) { x1 = q1; x2 = q2; }
        if (tid == 0)  { x1 = s01; x2 = s02; }

        // ---- Phase C: exact recurrence, y overwrites u in place ----
        up = up0; y1 = x1; y2 = x2;
        #pragma unroll
        for (int q = 0; q < NQ; ++q) {
            const int slot = swz(tid, q);
            float4 v = lds[slot];
            float4 o;
            IIR_STEP(v.x, o.x); IIR_STEP(v.y, o.y);
            IIR_STEP(v.z, o.z); IIR_STEP(v.w, o.w);
            lds[slot] = o;
        }
        if (tid == NCH - 1) { sh_carry[0] = y1; sh_carry[1] = y2; }
        __syncthreads();   // all y in LDS

        // ---- fused stage: y(half0) out (nt), prefetched u(half1) in ----
        if (h == 0) {
            #pragma unroll
            for (int s = 0; s < NSTG; ++s) {
                const int g = s * NCH + tid;
                const int slot = swz(g >> 3, g & 7);
                float4 o = lds[slot];
                nt_store4(&y4[g], o);
                lds[slot] = r[s];    // registers already resident — no vm wait
            }
        }
    }
#undef IIR_STEP

    // ---- stage out half 1 (nontemporal) ----
    #pragma unroll
    for (int s = 0; s < NSTG; ++s) {
        const int g = s * NCH + tid;
        nt_store4(&y4[(HALF / 4) + g], lds[swz(g >> 3, g & 7)]);
    }
}

extern "C" void kernel_launch(void* const* d_in, const int* in_sizes, int n_in,
                              void* d_out, int out_size, void* d_ws, size_t ws_size,
                              hipStream_t stream) {
    const float* b  = (const float*)d_in[0];
    const float* a  = (const float*)d_in[1];
    const float* u  = (const float*)d_in[2];
    const float* yi = (const float*)d_in[3];
    const float* ui = (const float*)d_in[4];
    float* yout = (float*)d_out;

    const int B = in_sizes[2] / T_LEN;   // 1024 rows
    iir_kernel<<<B, NCH, 0, stream>>>(b, a, u, yi, ui, yout);
}

// Round 6
// 147.072 us; speedup vs baseline: 1.0087x; 1.0087x over previous
//
#include <hip/hip_runtime.h>

// LinearSiso IIR, round 6: R5 structure with nontemporal stores REVERTED
// (measured 2x write amplification on gfx950: WRITE_SIZE 64->132 MB — nt
// bypasses L2 write-combining; plain coalesced float4 stores merge to full
// lines in L2). Keeps: early half-0 load issue, register prefetch of half-1
// during half-0 scan/Phase-C, fused stage-out/stage-in with no vm wait.

constexpr int T_LEN = 16384;
constexpr int HALF  = 8192;   // samples per half
constexpr int NCH   = 256;    // threads = chunks per half
constexpr int LCH   = 32;     // samples per chunk
constexpr int NQ    = 8;      // float4 quarters per chunk
constexpr int NSTG  = 8;      // stage iterations: HALF/4/NCH

// physical float4 slot for logical (chunk t, quarter q)
__device__ __forceinline__ int swz(int t, int q) {
    return t * NQ + (q ^ (t & (NQ - 1)));
}

__global__ __launch_bounds__(NCH, 4) void iir_kernel(
    const float* __restrict__ bco, const float* __restrict__ aco,
    const float* __restrict__ u,   const float* __restrict__ y_init,
    const float* __restrict__ u_init, float* __restrict__ y)
{
    __shared__ float4 lds[HALF / 4];       // 32 KB half-row buffer (swizzled)
    __shared__ float sh_wt1[4], sh_wt2[4]; // per-wave scan totals
    __shared__ float sh_carry[3];          // y[8191], y[8190], u[8191] of half0

    const int row  = blockIdx.x;
    const int tid  = threadIdx.x;
    const int lane = tid & 63;
    const int wave = tid >> 6;

    const float4* __restrict__ u4 = (const float4*)(u + (size_t)row * T_LEN);
    float4*       __restrict__ y4 = (float4*)(y + (size_t)row * T_LEN);
    const float*  ldsf = (const float*)lds;

    // ---- issue half-0 stage-in loads immediately (hide behind preamble) ----
    float4 r[NSTG];
    #pragma unroll
    for (int s = 0; s < NSTG; ++s) r[s] = u4[s * NCH + tid];

    const float b0 = bco[0], b1 = bco[1];
    const float a1 = aco[0], a2 = aco[1];

    // ---- chunk-transition matrix M (LCH steps) and powers M^(2^k), k=0..6 ----
    float pa = 1.f, pb = 0.f;
    #pragma unroll
    for (int k = 0; k <= LCH - 2; ++k) { float pn = fmaf(-a2, pb, -(a1 * pa)); pb = pa; pa = pn; }
    const float pL2 = pa, pL3 = pb;
    const float pL1 = fmaf(-a2, pL3, -(a1 * pL2));
    float m11[7], m12[7], m21[7], m22[7];
    m11[0] = pL1; m12[0] = -a2 * pL2; m21[0] = pL2; m22[0] = -a2 * pL3;
    #pragma unroll
    for (int k = 1; k < 7; ++k) {   // square
        m11[k] = fmaf(m11[k-1], m11[k-1], m12[k-1] * m21[k-1]);
        m12[k] = fmaf(m11[k-1], m12[k-1], m12[k-1] * m22[k-1]);
        m21[k] = fmaf(m21[k-1], m11[k-1], m22[k-1] * m21[k-1]);
        m22[k] = fmaf(m21[k-1], m12[k-1], m22[k-1] * m22[k-1]);
    }
    // per-lane P = M^(lane+1) via binary decomposition (powers commute)
    float P11 = 1.f, P12 = 0.f, P21 = 0.f, P22 = 1.f;
    {
        const int e = lane + 1;
        #pragma unroll
        for (int k = 0; k < 7; ++k) {
            if ((e >> k) & 1) {
                float n11 = fmaf(m11[k], P11, m12[k] * P21);
                float n12 = fmaf(m11[k], P12, m12[k] * P22);
                float n21 = fmaf(m21[k], P11, m22[k] * P21);
                float n22 = fmaf(m21[k], P12, m22[k] * P22);
                P11 = n11; P12 = n12; P21 = n21; P22 = n22;
            }
        }
    }

    // ---- commit half-0 stage-in to LDS ----
    #pragma unroll
    for (int s = 0; s < NSTG; ++s) {
        const int g = s * NCH + tid;
        lds[swz(g >> 3, g & 7)] = r[s];
    }

#define IIR_STEP(UC, OUTV)                                        \
    {                                                             \
        float x_ = fmaf(b0, (UC), b1 * up);                       \
        (OUTV) = fmaf(-a2, y2, fmaf(-a1, y1, x_));                \
        y2 = y1; y1 = (OUTV); up = (UC);                          \
    }

    #pragma unroll 1
    for (int h = 0; h < 2; ++h) {
        __syncthreads();   // staged u visible

        // u[chunk_base - 1]
        float up0;
        if (tid == 0) up0 = (h == 0) ? u_init[2 * row] : sh_carry[2];
        else          up0 = ldsf[swz(tid - 1, 7) * 4 + 3];

        // ---- Phase A: zero-state response of own chunk ----
        float up = up0, y1 = 0.f, y2 = 0.f;
        #pragma unroll
        for (int q = 0; q < NQ; ++q) {
            float4 v = lds[swz(tid, q)];
            float t0, t1, t2, t3;
            IIR_STEP(v.x, t0); IIR_STEP(v.y, t1);
            IIR_STEP(v.z, t2); IIR_STEP(v.w, t3);
            (void)t0; (void)t1; (void)t2; (void)t3;
        }
        float v1 = y1, v2 = y2;                 // e_c
        if (tid == NCH - 1 && h == 0) sh_carry[2] = up;   // u[8191]

        // ---- prefetch half-1 u into registers; loads fly during scan + C ----
        if (h == 0) {
            #pragma unroll
            for (int s = 0; s < NSTG; ++s)
                r[s] = u4[(HALF / 4) + s * NCH + tid];
        }

        // fold initial state into e_0:  e'_0 = e_0 + M s0
        float s01 = 0.f, s02 = 0.f;
        if (tid == 0) {
            s01 = (h == 0) ? y_init[2 * row]     : sh_carry[0];
            s02 = (h == 0) ? y_init[2 * row + 1] : sh_carry[1];
            v1 = fmaf(m11[0], s01, fmaf(m12[0], s02, v1));
            v2 = fmaf(m21[0], s01, fmaf(m22[0], s02, v2));
        }

        // ---- intra-wave inclusive scan: v_c += M^d v_{c-d}, d=1..32 ----
        #pragma unroll
        for (int k = 0; k < 6; ++k) {
            const int d = 1 << k;
            float t1 = __shfl_up(v1, d);
            float t2 = __shfl_up(v2, d);
            if (lane >= d) {
                v1 = fmaf(m11[k], t1, fmaf(m12[k], t2, v1));
                v2 = fmaf(m21[k], t1, fmaf(m22[k], t2, v2));
            }
        }
        if (lane == 63) { sh_wt1[wave] = v1; sh_wt2[wave] = v2; }
        __syncthreads();

        // ---- cross-wave: Q_w = sum_{v<w} M^64(w-1-v) W_v ----
        float q1 = 0.f, q2 = 0.f;
        for (int w = 0; w < wave; ++w) {
            float n1 = fmaf(m11[6], q1, fmaf(m12[6], q2, sh_wt1[w]));
            float n2 = fmaf(m21[6], q1, fmaf(m22[6], q2, sh_wt2[w]));
            q1 = n1; q2 = n2;
        }
        // global inclusive prefix for this thread
        float w1 = fmaf(P11, q1, fmaf(P12, q2, v1));
        float w2 = fmaf(P21, q1, fmaf(P22, q2, v2));
        // exclusive: start state s_c = w'_{c-1}
        float x1 = __shfl_up(w1, 1);
        float x2 = __shfl_up(w2, 1);
        if (lane == 0) { x1 = q1; x2 = q2; }
        if (tid == 0)  { x1 = s01; x2 = s02; }

        // ---- Phase C: exact recurrence, y overwrites u in place ----
        up = up0; y1 = x1; y2 = x2;
        #pragma unroll
        for (int q = 0; q < NQ; ++q) {
            const int slot = swz(tid, q);
            float4 v = lds[slot];
            float4 o;
            IIR_STEP(v.x, o.x); IIR_STEP(v.y, o.y);
            IIR_STEP(v.z, o.z); IIR_STEP(v.w, o.w);
            lds[slot] = o;
        }
        if (tid == NCH - 1) { sh_carry[0] = y1; sh_carry[1] = y2; }
        __syncthreads();   // all y in LDS

        // ---- fused stage: y(half0) out, prefetched u(half1) in ----
        if (h == 0) {
            #pragma unroll
            for (int s = 0; s < NSTG; ++s) {
                const int g = s * NCH + tid;
                const int slot = swz(g >> 3, g & 7);
                float4 o = lds[slot];
                y4[g] = o;
                lds[slot] = r[s];    // registers already resident — no vm wait
            }
        }
    }
#undef IIR_STEP

    // ---- stage out half 1 ----
    #pragma unroll
    for (int s = 0; s < NSTG; ++s) {
        const int g = s * NCH + tid;
        y4[(HALF / 4) + g] = lds[swz(g >> 3, g & 7)];
    }
}

extern "C" void kernel_launch(void* const* d_in, const int* in_sizes, int n_in,
                              void* d_out, int out_size, void* d_ws, size_t ws_size,
                              hipStream_t stream) {
    const float* b  = (const float*)d_in[0];
    const float* a  = (const float*)d_in[1];
    const float* u  = (const float*)d_in[2];
    const float* yi = (const float*)d_in[3];
    const float* ui = (const float*)d_in[4];
    float* yout = (float*)d_out;

    const int B = in_sizes[2] / T_LEN;   // 1024 rows
    iir_kernel<<<B, NCH, 0, stream>>>(b, a, u, yi, ui, yout);
}